// Round 6
// baseline (709.192 us; speedup 1.0000x reference)
//
#include <hip/hip_runtime.h>
#include <hip/hip_bf16.h>

// ---------------- constants ----------------
#define SEQ      2048
#define BATCH    2
#define DMODEL   1024
#define NHEADS   16
#define HDIM     64
#define FFN_DIM  4096
#define MROWS    (BATCH*SEQ)   // 4096

typedef __attribute__((ext_vector_type(8))) short bf16x8;
typedef __attribute__((ext_vector_type(4))) float f32x4;

#define GFENCE() asm volatile("" ::: "memory")
#define SBAR()   do { GFENCE(); __builtin_amdgcn_s_barrier(); GFENCE(); } while (0)

// ---------------- helpers ----------------
__device__ __forceinline__ unsigned short f2b(float f) {
    union { float f; unsigned int u; } v; v.f = f;
    unsigned int u = v.u;
    return (unsigned short)((u + 0x7FFFu + ((u >> 16) & 1u)) >> 16);  // RNE
}
__device__ __forceinline__ float b2f(unsigned short h) {
    union { unsigned int u; float f; } v; v.u = ((unsigned int)h) << 16;
    return v.f;
}
__device__ __forceinline__ void gload_lds16(const void* g, void* l) {
    __builtin_amdgcn_global_load_lds((const __attribute__((address_space(1))) void*)g,
                                     (__attribute__((address_space(3))) void*)l, 16, 0, 0);
}

// ---------------- prep: all weight transposes + activation casts, ONE dispatch ----------------
// seg layout (blocks): 0..3071 Wqkv | ..4095 Wo1 | ..6143 Wkv | ..7167 Wq | ..8191 Wo2
//                      | ..12287 W1 | ..16383 W2 | ..18431 cast x | ..20479 cast y
__device__ __forceinline__ void trans_tile(const float* __restrict__ W,
                                           unsigned short* __restrict__ Wt,
                                           int K, int N, int local) {
    __shared__ float t[32][33];
    const int ntx = N >> 5;
    const int bx = local % ntx, by = local / ntx;
    const int n0 = bx * 32, k0 = by * 32;
    const int tx = threadIdx.x & 31, ty = threadIdx.x >> 5;   // 32 x 8
#pragma unroll
    for (int i = 0; i < 4; i++)
        t[ty + i * 8][tx] = W[(size_t)(k0 + ty + i * 8) * N + n0 + tx];
    __syncthreads();
#pragma unroll
    for (int i = 0; i < 4; i++) {
        const int n = ty + i * 8;
        Wt[(size_t)(n0 + n) * K + k0 + tx] = f2b(t[tx][n]);
    }
}
__device__ __forceinline__ void cast_blk(const float* __restrict__ in,
                                         unsigned short* __restrict__ out, int local) {
    const int i = (local * 256 + threadIdx.x) * 8;
    float4 a = *(const float4*)(in + i);
    float4 b = *(const float4*)(in + i + 4);
    unsigned short r[8] = {f2b(a.x), f2b(a.y), f2b(a.z), f2b(a.w),
                           f2b(b.x), f2b(b.y), f2b(b.z), f2b(b.w)};
    *(uint4*)(out + i) = *(const uint4*)r;
}

__global__ __launch_bounds__(256) void prep(
    const float* Wqkv, const float* Wo1, const float* Wkv, const float* Wq,
    const float* Wo2, const float* W1, const float* W2,
    const float* x, const float* y,
    unsigned short* pWqkvT, unsigned short* pWo1T, unsigned short* pWkvT,
    unsigned short* pWqT, unsigned short* pWo2T, unsigned short* pW1T,
    unsigned short* pW2T, unsigned short* pxbf, unsigned short* pybf) {
    const int bid = blockIdx.x;
    if      (bid < 3072)  trans_tile(Wqkv, pWqkvT, 1024, 3072, bid);
    else if (bid < 4096)  trans_tile(Wo1,  pWo1T,  1024, 1024, bid - 3072);
    else if (bid < 6144)  trans_tile(Wkv,  pWkvT,  1024, 2048, bid - 4096);
    else if (bid < 7168)  trans_tile(Wq,   pWqT,   1024, 1024, bid - 6144);
    else if (bid < 8192)  trans_tile(Wo2,  pWo2T,  1024, 1024, bid - 7168);
    else if (bid < 12288) trans_tile(W1,   pW1T,   1024, 4096, bid - 8192);
    else if (bid < 16384) trans_tile(W2,   pW2T,   4096, 1024, bid - 12288);
    else if (bid < 18432) cast_blk(x, pxbf, bid - 16384);
    else                  cast_blk(y, pybf, bid - 18432);
}

// ---------------- bf16 MFMA GEMM (128x128, 2-barrier): C = A @ Bt^T + bias ----------------
template <int RELU, int WF32, int WB16>
__global__ __launch_bounds__(256) void gemm_bt(const unsigned short* __restrict__ A,
                                               const unsigned short* __restrict__ Bt,
                                               const float* __restrict__ bias,
                                               float* __restrict__ Cf,
                                               unsigned short* __restrict__ Cb,
                                               int M, int N, int K) {
    __shared__ __align__(16) unsigned short As[128 * 32];
    __shared__ __align__(16) unsigned short Bs[128 * 32];
    const int tid  = threadIdx.x;
    const int lane = tid & 63;
    const int w    = tid >> 6;
    const int m0   = blockIdx.y << 7;
    const int n0   = blockIdx.x << 7;
    const int wr   = (w >> 1) << 6;
    const int wc   = (w & 1) << 6;
    const int srow = lane >> 2;
    const int scol = (lane & 3) << 3;

    f32x4 acc[4][4];
#pragma unroll
    for (int mi = 0; mi < 4; mi++)
#pragma unroll
        for (int ni = 0; ni < 4; ni++) acc[mi][ni] = (f32x4){0.f, 0.f, 0.f, 0.f};

    for (int k0 = 0; k0 < K; k0 += 32) {
#pragma unroll
        for (int t = 0; t < 2; t++) {
            const int rg  = w * 2 + t;
            const int row = (rg << 4) + srow;
            gload_lds16(A  + (size_t)(m0 + row) * K + k0 + scol, (char*)As + (rg << 10));
            gload_lds16(Bt + (size_t)(n0 + row) * K + k0 + scol, (char*)Bs + (rg << 10));
        }
        __syncthreads();
        const int fr = lane & 15;
        const int fk = (lane >> 4) << 3;
        bf16x8 af[4], bfr[4];
#pragma unroll
        for (int i = 0; i < 4; i++) {
            af[i]  = *(const bf16x8*)(As + (wr + (i << 4) + fr) * 32 + fk);
            bfr[i] = *(const bf16x8*)(Bs + (wc + (i << 4) + fr) * 32 + fk);
        }
#pragma unroll
        for (int mi = 0; mi < 4; mi++)
#pragma unroll
            for (int ni = 0; ni < 4; ni++)
                acc[mi][ni] = __builtin_amdgcn_mfma_f32_16x16x32_bf16(af[mi], bfr[ni], acc[mi][ni], 0, 0, 0);
        __syncthreads();
    }

    const int fr = lane & 15;
    const int fq = lane >> 4;
#pragma unroll
    for (int mi = 0; mi < 4; mi++) {
#pragma unroll
        for (int ni = 0; ni < 4; ni++) {
            const int col = n0 + wc + (ni << 4) + fr;
            const float bv = bias[col];
#pragma unroll
            for (int i = 0; i < 4; i++) {
                const int row = m0 + wr + (mi << 4) + (fq << 2) + i;
                float v = acc[mi][ni][i] + bv;
                if (RELU) v = fmaxf(v, 0.f);
                if (WF32) Cf[(size_t)row * N + col] = v;
                if (WB16) Cb[(size_t)row * N + col] = f2b(v);
            }
        }
    }
}

// ---------------- bf16 MFMA GEMM (256x256, 8-wave, 4-phase counted-vmcnt dbuf) ----------------
template <int RELU, int WF32, int WB16>
__global__ __launch_bounds__(512, 2) void gemm256(const unsigned short* __restrict__ A,
                                                  const unsigned short* __restrict__ Bt,
                                                  const float* __restrict__ bias,
                                                  float* __restrict__ Cf,
                                                  unsigned short* __restrict__ Cb,
                                                  int M, int N, int K) {
    __shared__ __align__(16) unsigned short lds[2][2][256 * 64];   // [buf][0=A,1=B]
    const int tid  = threadIdx.x;
    const int lane = tid & 63;
    const int w    = tid >> 6;        // 0..7
    const int q15  = lane & 15;
    const int g    = lane >> 4;       // 0..3
    const int m0   = blockIdx.y << 8;
    const int n0   = blockIdx.x << 8;
    const int wr   = (w >> 2) << 7;   // 0 / 128
    const int wc   = (w & 3) << 6;    // 0 / 64 / 128 / 192

    f32x4 acc[8][4];
#pragma unroll
    for (int m = 0; m < 8; m++)
#pragma unroll
        for (int n = 0; n < 4; n++) acc[m][n] = (f32x4){0.f, 0.f, 0.f, 0.f};

    const int NT = K >> 6;

    auto stage = [&](int which, int buf, int h, int kt, const unsigned short* src, int base0) {
        char* ldsb = (char*)&lds[buf][which][0];
#pragma unroll
        for (int j = 0; j < 2; j++) {
            const int c    = (w << 7) + (j << 6) + lane;
            const int r    = c >> 3, ci = c & 7;
            const int trow = ((r >> 6) << 7) + (h << 6) + (r & 63);
            const int r0   = (w << 4) + (j << 3);
            const int tr0  = ((r0 >> 6) << 7) + (h << 6) + (r0 & 63);
            gload_lds16(src + (size_t)(base0 + trow) * K + (kt << 6) + ((ci ^ (r & 7)) << 3),
                        ldsb + tr0 * 128);
        }
    };
    auto ldA = [&](int buf, int row, int kc) -> bf16x8 {
        return *(const bf16x8*)((const char*)&lds[buf][0][0] + row * 128 + ((kc ^ (row & 7)) << 4));
    };
    auto ldB = [&](int buf, int row, int kc) -> bf16x8 {
        return *(const bf16x8*)((const char*)&lds[buf][1][0] + row * 128 + ((kc ^ (row & 7)) << 4));
    };

    stage(1, 0, 0, 0, Bt, n0);
    stage(1, 0, 1, 0, Bt, n0);
    stage(0, 0, 0, 0, A, m0);
    stage(0, 0, 1, 0, A, m0);

    for (int t = 0; t < NT; ++t) {
        const int buf = t & 1, nb = buf ^ 1;
        const bool st = (t + 1 < NT);
        bf16x8 bfr[4], af[4];

        if (st) { stage(1, nb, 0, t + 1, Bt, n0);
                  asm volatile("s_waitcnt vmcnt(4)" ::: "memory"); }
        else    { asm volatile("s_waitcnt vmcnt(2)" ::: "memory"); }
        SBAR();
#pragma unroll
        for (int n = 0; n < 4; n++) bfr[n] = ldB(buf, wc + n * 16 + q15, g);
#pragma unroll
        for (int m = 0; m < 4; m++) af[m]  = ldA(buf, wr + m * 16 + q15, g);
        __builtin_amdgcn_s_setprio(1);
#pragma unroll
        for (int m = 0; m < 4; m++)
#pragma unroll
            for (int n = 0; n < 4; n++)
                acc[m][n] = __builtin_amdgcn_mfma_f32_16x16x32_bf16(af[m], bfr[n], acc[m][n], 0, 0, 0);
        __builtin_amdgcn_s_setprio(0);
        SBAR();

        if (st) { stage(1, nb, 1, t + 1, Bt, n0);
                  asm volatile("s_waitcnt vmcnt(4)" ::: "memory"); }
        else    { asm volatile("s_waitcnt vmcnt(0)" ::: "memory"); }
        SBAR();
#pragma unroll
        for (int m = 0; m < 4; m++) af[m] = ldA(buf, wr + 64 + m * 16 + q15, g);
        __builtin_amdgcn_s_setprio(1);
#pragma unroll
        for (int m = 0; m < 4; m++)
#pragma unroll
            for (int n = 0; n < 4; n++)
                acc[4 + m][n] = __builtin_amdgcn_mfma_f32_16x16x32_bf16(af[m], bfr[n], acc[4 + m][n], 0, 0, 0);
        __builtin_amdgcn_s_setprio(0);
        SBAR();

        if (st) stage(0, nb, 0, t + 1, A, m0);
        SBAR();
#pragma unroll
        for (int n = 0; n < 4; n++) bfr[n] = ldB(buf, wc + n * 16 + q15, 4 + g);
#pragma unroll
        for (int m = 0; m < 4; m++) af[m]  = ldA(buf, wr + m * 16 + q15, 4 + g);
        __builtin_amdgcn_s_setprio(1);
#pragma unroll
        for (int m = 0; m < 4; m++)
#pragma unroll
            for (int n = 0; n < 4; n++)
                acc[m][n] = __builtin_amdgcn_mfma_f32_16x16x32_bf16(af[m], bfr[n], acc[m][n], 0, 0, 0);
        __builtin_amdgcn_s_setprio(0);
        SBAR();

        if (st) stage(0, nb, 1, t + 1, A, m0);
        SBAR();
#pragma unroll
        for (int m = 0; m < 4; m++) af[m] = ldA(buf, wr + 64 + m * 16 + q15, 4 + g);
        __builtin_amdgcn_s_setprio(1);
#pragma unroll
        for (int m = 0; m < 4; m++)
#pragma unroll
            for (int n = 0; n < 4; n++)
                acc[4 + m][n] = __builtin_amdgcn_mfma_f32_16x16x32_bf16(af[m], bfr[n], acc[4 + m][n], 0, 0, 0);
        __builtin_amdgcn_s_setprio(0);
        SBAR();
    }

#pragma unroll
    for (int mh = 0; mh < 2; mh++)
#pragma unroll
        for (int mf = 0; mf < 4; mf++)
#pragma unroll
            for (int nf = 0; nf < 4; nf++) {
                const int col = n0 + wc + nf * 16 + q15;
                const float bv = bias[col];
#pragma unroll
                for (int i = 0; i < 4; i++) {
                    const int row = m0 + wr + mh * 64 + mf * 16 + (g << 2) + i;
                    float v = acc[mh * 4 + mf][nf][i] + bv;
                    if (RELU) v = fmaxf(v, 0.f);
                    if (WF32) Cf[(size_t)row * N + col] = v;
                    if (WB16) Cb[(size_t)row * N + col] = f2b(v);
                }
            }
}

// ---------------- residual + LayerNorm (row = 1024) ----------------
template <int WB16>
__global__ __launch_bounds__(256) void resid_ln(const float* __restrict__ xin,
                                                const float* __restrict__ res,
                                                const float* __restrict__ g,
                                                const float* __restrict__ b,
                                                float* __restrict__ outf,
                                                unsigned short* __restrict__ outb) {
    const int row = blockIdx.x;
    const int tid = threadIdx.x;
    const size_t base = (size_t)row * 1024 + tid * 4;
    float4 xv = *(const float4*)(xin + base);
    float4 rv = *(const float4*)(res + base);
    const float v0 = xv.x + rv.x, v1 = xv.y + rv.y, v2 = xv.z + rv.z, v3 = xv.w + rv.w;
    float s  = v0 + v1 + v2 + v3;
    float sq = v0 * v0 + v1 * v1 + v2 * v2 + v3 * v3;
#pragma unroll
    for (int off = 32; off; off >>= 1) { s += __shfl_xor(s, off); sq += __shfl_xor(sq, off); }
    __shared__ float red[8];
    if ((tid & 63) == 0) { red[tid >> 6] = s; red[4 + (tid >> 6)] = sq; }
    __syncthreads();
    s  = red[0] + red[1] + red[2] + red[3];
    sq = red[4] + red[5] + red[6] + red[7];
    const float mean = s * (1.0f / 1024.0f);
    const float var  = sq * (1.0f / 1024.0f) - mean * mean;
    const float inv  = rsqrtf(var + 1e-5f);
    const int col = tid * 4;
    float4 gv = *(const float4*)(g + col);
    float4 bv = *(const float4*)(b + col);
    const float o0 = (v0 - mean) * inv * gv.x + bv.x;
    const float o1 = (v1 - mean) * inv * gv.y + bv.y;
    const float o2 = (v2 - mean) * inv * gv.z + bv.z;
    const float o3 = (v3 - mean) * inv * gv.w + bv.w;
    float4 ov = {o0, o1, o2, o3};
    *(float4*)(outf + base) = ov;
    if (WB16) {
        uint2 u;
        u.x = (unsigned int)f2b(o0) | ((unsigned int)f2b(o1) << 16);
        u.y = (unsigned int)f2b(o2) | ((unsigned int)f2b(o3) << 16);
        *(uint2*)(outb + base) = u;
    }
}

// ---------------- MFMA flash attention v2: QBLK=128 (8 waves), KVBLK=64, defer-max ----------------
// LDS: K 8KB + Vraw 8KB + QVt 16KB (Q prologue / Vt after) + P 8x2KB = 48KB -> 3 blocks/CU.
// Staging amortized over 8 waves; V-transpose: d=lane (conflict-free), kv-group = wave.
__global__ __launch_bounds__(512) void attn_mfma2(
    const unsigned short* __restrict__ Qb, int q_rs, int q_ho,
    const unsigned short* __restrict__ Kb, int k_rs, int k_ho,
    const unsigned short* __restrict__ Vb, int v_rs, int v_ho,
    const float* __restrict__ mask,
    unsigned short* __restrict__ Ob, int o_rs, int o_ho) {
    __shared__ __align__(16) unsigned short Kls[64 * 64];
    __shared__ __align__(16) unsigned short Vraw[64 * 64];
    __shared__ __align__(16) unsigned short QVt[128 * 64];   // Q (prologue, 16KB) then Vt (8KB)
    __shared__ __align__(16) unsigned short Pls[8][16 * 64];

    const int tid  = threadIdx.x;
    const int lane = tid & 63;
    const int w    = tid >> 6;        // 0..7
    const int g    = lane >> 4;
    const int q15  = lane & 15;
    const int swz  = (lane & 7) << 4;
    const int bh   = blockIdx.y;
    const int b    = bh >> 4, h = bh & 15;
    const int q0   = blockIdx.x << 7;   // QBLK=128
    const size_t rowbase = (size_t)b * SEQ;

    char* Kc = (char*)Kls;
    char* Vc = (char*)Vraw;
    char* Tc = (char*)QVt;
    char* Pc = (char*)(&Pls[w][0]);

    const int hq = h * q_ho, hk = h * k_ho, hv = h * v_ho;

    // stage a 64-row tile: 512 chunks, one per thread
    auto stage64 = [&](const unsigned short* base, int rs, int hoff, int row0, char* ldsb) {
        const int c = tid;
        const int r = c >> 3, ci = c & 7;
        gload_lds16(base + (rowbase + row0 + r) * (size_t)rs + hoff + ((ci ^ (r & 7)) << 3),
                    ldsb + ((c >> 6) << 10));
    };

    // prologue: stage Q (128 rows, 2 chunks/thread), K(0), V(0)
#pragma unroll
    for (int bb = 0; bb < 2; bb++) {
        const int c = tid + (bb << 9);
        const int r = c >> 3, ci = c & 7;
        gload_lds16(Qb + (rowbase + q0 + r) * (size_t)q_rs + hq + ((ci ^ (r & 7)) << 3),
                    Tc + ((c >> 6) << 10));
    }
    stage64(Kb, k_rs, hk, 0, Kc);
    stage64(Vb, v_rs, hv, 0, Vc);

    float m_run = -3.0e38f, l_run = 0.f;
    f32x4 oacc[4];
#pragma unroll
    for (int fd = 0; fd < 4; fd++) oacc[fd] = (f32x4){0.f, 0.f, 0.f, 0.f};

    __syncthreads();
    bf16x8 qf[2];
#pragma unroll
    for (int s = 0; s < 2; s++)
        qf[s] = *(const bf16x8*)(Tc + (w * 16 + q15) * 128 + (((s << 6) + (g << 4)) ^ swz));
    __syncthreads();   // Q_lds free -> Vt

    const float* mrow_ptr = mask + (size_t)(q0 + w * 16 + q15) * SEQ;

    for (int t = 0; t < 32; t++) {
        const int kv0 = t << 6;
        // ---- V transpose: Vraw[kv][d] -> Vt[d=lane][kv-group=w], conflict-free lanes ----
        {
            unsigned short t8[8];
#pragma unroll
            for (int m = 0; m < 8; m++)
                t8[m] = *(const unsigned short*)(Vc + (w * 8 + m) * 128 + ((2 * lane) ^ (m << 4)));
            *(uint4*)(Tc + lane * 128 + ((w << 4) ^ swz)) = *(const uint4*)t8;
        }
        // ---- QK^T (swapped): sacc[f] = S^T[kv=f*16+g*4+r][q=q15] ----
        f32x4 sacc[4];
#pragma unroll
        for (int f = 0; f < 4; f++) sacc[f] = (f32x4){0.f, 0.f, 0.f, 0.f};
#pragma unroll
        for (int s = 0; s < 2; s++)
#pragma unroll
            for (int f = 0; f < 4; f++) {
                bf16x8 kf = *(const bf16x8*)(Kc + (f * 16 + q15) * 128 + (((s << 6) + (g << 4)) ^ swz));
                sacc[f] = __builtin_amdgcn_mfma_f32_16x16x32_bf16(kf, qf[s], sacc[f], 0, 0, 0);
            }
        // ---- online softmax with defer-max (THR=8) ----
        float p[4][4];
        float mt = -3.0e38f;
#pragma unroll
        for (int f = 0; f < 4; f++) {
            float4 mk = *(const float4*)(mrow_ptr + kv0 + f * 16 + g * 4);
            const float* mkp = (const float*)&mk;
#pragma unroll
            for (int r = 0; r < 4; r++) {
                const float v = sacc[f][r] * 0.125f + mkp[r];
                p[f][r] = v;
                mt = fmaxf(mt, v);
            }
        }
        mt = fmaxf(mt, __shfl_xor(mt, 16));
        mt = fmaxf(mt, __shfl_xor(mt, 32));
        bool rescale = !__all(mt <= m_run + 8.0f);
        float alpha = 1.0f;
        if (rescale) {
            const float mnew = fmaxf(m_run, mt);
            alpha = __expf(m_run - mnew);
            m_run = mnew;
        }
        float lsum = 0.f;
#pragma unroll
        for (int f = 0; f < 4; f++)
#pragma unroll
            for (int r = 0; r < 4; r++) {
                const float e = __expf(p[f][r] - m_run);
                p[f][r] = e;
                lsum += e;
            }
        lsum += __shfl_xor(lsum, 16);
        lsum += __shfl_xor(lsum, 32);
        l_run = l_run * alpha + lsum;
        // ---- P -> bf16 into per-wave P_lds ----
#pragma unroll
        for (int f = 0; f < 4; f++) {
            const unsigned int w0 = (unsigned int)f2b(p[f][0]) | ((unsigned int)f2b(p[f][1]) << 16);
            const unsigned int w1 = (unsigned int)f2b(p[f][2]) | ((unsigned int)f2b(p[f][3]) << 16);
            const int bbase = ((f << 5) + (g << 3)) ^ swz;
            *(unsigned int*)(Pc + q15 * 128 + bbase)     = w0;
            *(unsigned int*)(Pc + q15 * 128 + bbase + 4) = w1;
        }
        __syncthreads();   // Vt+P complete; K/Vraw consumed
        if (t < 31) {      // prefetch next K/V (overlaps PV; drained by loop-end syncthreads)
            stage64(Kb, k_rs, hk, kv0 + 64, Kc);
            stage64(Vb, v_rs, hv, kv0 + 64, Vc);
        }
        // ---- rescale O (skipped when defer-max holds) ----
        if (rescale) {
            float ar[4];
#pragma unroll
            for (int r = 0; r < 4; r++) ar[r] = __shfl(alpha, (g << 4) + (g << 2) + r);
#pragma unroll
            for (int fd = 0; fd < 4; fd++)
#pragma unroll
                for (int r = 0; r < 4; r++) oacc[fd][r] *= ar[r];
        }
        // ---- PV ----
#pragma unroll
        for (int s = 0; s < 2; s++) {
            const bf16x8 pf = *(const bf16x8*)(Pc + q15 * 128 + (((s << 6) + (g << 4)) ^ swz));
#pragma unroll
            for (int fd = 0; fd < 4; fd++) {
                const bf16x8 vf = *(const bf16x8*)(Tc + (fd * 16 + q15) * 128 + (((s << 6) + (g << 4)) ^ swz));
                oacc[fd] = __builtin_amdgcn_mfma_f32_16x16x32_bf16(pf, vf, oacc[fd], 0, 0, 0);
            }
        }
        __syncthreads();   // PV done; next-tile K/V landed (vmcnt drained by barrier)
    }

    const float rl = 1.0f / l_run;
    float invr[4];
#pragma unroll
    for (int r = 0; r < 4; r++) invr[r] = __shfl(rl, (g << 4) + (g << 2) + r);
    const size_t orow0 = rowbase + q0 + w * 16;
#pragma unroll
    for (int fd = 0; fd < 4; fd++)
#pragma unroll
        for (int r = 0; r < 4; r++) {
            const int qq = (g << 2) + r;
            Ob[(orow0 + qq) * (size_t)o_rs + h * o_ho + fd * 16 + q15] = f2b(oacc[fd][r] * invr[r]);
        }
}

// ---------------- orchestration ----------------
extern "C" void kernel_launch(void* const* d_in, const int* in_sizes, int n_in,
                              void* d_out, int out_size, void* d_ws, size_t ws_size,
                              hipStream_t stream) {
    const float* x     = (const float*)d_in[0];
    const float* y     = (const float*)d_in[1];
    const float* mask1 = (const float*)d_in[2];
    const float* mask2 = (const float*)d_in[3];
    const float* Wqkv  = (const float*)d_in[4];
    const float* bqkv  = (const float*)d_in[5];
    const float* Wo1   = (const float*)d_in[6];
    const float* bo1   = (const float*)d_in[7];
    const float* Wkv   = (const float*)d_in[8];
    const float* bkv   = (const float*)d_in[9];
    const float* Wq    = (const float*)d_in[10];
    const float* bq    = (const float*)d_in[11];
    const float* Wo2   = (const float*)d_in[12];
    const float* bo2   = (const float*)d_in[13];
    const float* g1    = (const float*)d_in[14];
    const float* b1    = (const float*)d_in[15];
    const float* g2    = (const float*)d_in[16];
    const float* b2    = (const float*)d_in[17];
    const float* g3    = (const float*)d_in[18];
    const float* b3    = (const float*)d_in[19];
    const float* W1    = (const float*)d_in[20];
    const float* bw1   = (const float*)d_in[21];
    const float* W2    = (const float*)d_in[22];
    const float* bw2   = (const float*)d_in[23];

    char* ws = (char*)d_ws;
    const size_t o_WqkvT = 0;
    const size_t o_Wo1T  = o_WqkvT + 6291456;
    const size_t o_WkvT  = o_Wo1T  + 2097152;
    const size_t o_WqT   = o_WkvT  + 4194304;
    const size_t o_Wo2T  = o_WqT   + 2097152;
    const size_t o_W1T   = o_Wo2T  + 2097152;
    const size_t o_W2T   = o_W1T   + 8388608;
    const size_t o_xbf   = o_W2T   + 8388608;
    const size_t o_ybf   = o_xbf   + 8388608;
    const size_t o_qkv   = o_ybf   + 8388608;
    const size_t o_vals  = o_qkv   + 25165824;
    const size_t o_tmp   = o_vals  + 8388608;
    const size_t o_y1    = o_tmp   + 16777216;
    const size_t o_y1bf  = o_y1    + 16777216;
    const size_t o_y2    = o_y1bf  + 8388608;
    const size_t o_y2bf  = o_y2    + 16777216;
    const size_t o_kv    = o_qkv;
    const size_t o_q2    = o_qkv + 16777216;
    const size_t o_hbf   = o_xbf;

    unsigned short* pWqkvT = (unsigned short*)(ws + o_WqkvT);
    unsigned short* pWo1T  = (unsigned short*)(ws + o_Wo1T);
    unsigned short* pWkvT  = (unsigned short*)(ws + o_WkvT);
    unsigned short* pWqT   = (unsigned short*)(ws + o_WqT);
    unsigned short* pWo2T  = (unsigned short*)(ws + o_Wo2T);
    unsigned short* pW1T   = (unsigned short*)(ws + o_W1T);
    unsigned short* pW2T   = (unsigned short*)(ws + o_W2T);
    unsigned short* pxbf   = (unsigned short*)(ws + o_xbf);
    unsigned short* pybf   = (unsigned short*)(ws + o_ybf);
    unsigned short* pqkv   = (unsigned short*)(ws + o_qkv);
    unsigned short* pvals  = (unsigned short*)(ws + o_vals);
    float*          ptmp   = (float*)(ws + o_tmp);
    float*          py1    = (float*)(ws + o_y1);
    unsigned short* py1bf  = (unsigned short*)(ws + o_y1bf);
    float*          py2    = (float*)(ws + o_y2);
    unsigned short* py2bf  = (unsigned short*)(ws + o_y2bf);
    unsigned short* pkv    = (unsigned short*)(ws + o_kv);
    unsigned short* pq2    = (unsigned short*)(ws + o_q2);
    unsigned short* phbf   = (unsigned short*)(ws + o_hbf);

    // ---- one prep dispatch: 7 transposes + 2 casts ----
    prep<<<dim3(20480), dim3(256), 0, stream>>>(Wqkv, Wo1, Wkv, Wq, Wo2, W1, W2, x, y,
                                                pWqkvT, pWo1T, pWkvT, pWqT, pWo2T,
                                                pW1T, pW2T, pxbf, pybf);

    // ---- self-attention ----
    gemm256<0, 0, 1><<<dim3(3072 / 256, MROWS / 256), dim3(512), 0, stream>>>(
        pybf, pWqkvT, bqkv, nullptr, pqkv, MROWS, 3072, 1024);
    attn_mfma2<<<dim3(SEQ / 128, BATCH * NHEADS), dim3(512), 0, stream>>>(
        pqkv, 3072, 192, pqkv + 64, 3072, 192, pqkv + 128, 3072, 192,
        mask1, pvals, 1024, 64);
    gemm_bt<0, 1, 0><<<dim3(1024 / 128, MROWS / 128), dim3(256), 0, stream>>>(
        pvals, pWo1T, bo1, ptmp, nullptr, MROWS, 1024, 1024);
    resid_ln<1><<<dim3(MROWS), dim3(256), 0, stream>>>(ptmp, y, g1, b1, py1, py1bf);

    // ---- cross-attention ----
    gemm256<0, 0, 1><<<dim3(2048 / 256, MROWS / 256), dim3(512), 0, stream>>>(
        pxbf, pWkvT, bkv, nullptr, pkv, MROWS, 2048, 1024);
    gemm_bt<0, 0, 1><<<dim3(1024 / 128, MROWS / 128), dim3(256), 0, stream>>>(
        py1bf, pWqT, bq, nullptr, pq2, MROWS, 1024, 1024);
    attn_mfma2<<<dim3(SEQ / 128, BATCH * NHEADS), dim3(512), 0, stream>>>(
        pq2, 1024, 64, pkv, 2048, 128, pkv + 64, 2048, 128,
        mask2, pvals, 1024, 64);
    gemm_bt<0, 1, 0><<<dim3(1024 / 128, MROWS / 128), dim3(256), 0, stream>>>(
        pvals, pWo2T, bo2, ptmp, nullptr, MROWS, 1024, 1024);
    resid_ln<1><<<dim3(MROWS), dim3(256), 0, stream>>>(ptmp, py1, g2, b2, py2, py2bf);

    // ---- FFN ----
    gemm256<1, 0, 1><<<dim3(4096 / 256, MROWS / 256), dim3(512), 0, stream>>>(
        py2bf, pW1T, bw1, nullptr, phbf, MROWS, 4096, 1024);
    gemm_bt<0, 1, 0><<<dim3(1024 / 128, MROWS / 128), dim3(256), 0, stream>>>(
        phbf, pW2T, bw2, ptmp, nullptr, MROWS, 1024, 4096);
    resid_ln<0><<<dim3(MROWS), dim3(256), 0, stream>>>(ptmp, py2, g3, b3, (float*)d_out, nullptr);
}

// Round 8
// 655.274 us; speedup vs baseline: 1.0823x; 1.0823x over previous
//
#include <hip/hip_runtime.h>
#include <hip/hip_bf16.h>

// ---------------- constants ----------------
#define SEQ      2048
#define BATCH    2
#define DMODEL   1024
#define NHEADS   16
#define HDIM     64
#define FFN_DIM  4096
#define MROWS    (BATCH*SEQ)   // 4096

typedef __attribute__((ext_vector_type(8))) short bf16x8;
typedef __attribute__((ext_vector_type(4))) float f32x4;

#define GFENCE() asm volatile("" ::: "memory")
#define SBAR()   do { GFENCE(); __builtin_amdgcn_s_barrier(); GFENCE(); } while (0)

// ---------------- helpers ----------------
__device__ __forceinline__ unsigned short f2b(float f) {
    union { float f; unsigned int u; } v; v.f = f;
    unsigned int u = v.u;
    return (unsigned short)((u + 0x7FFFu + ((u >> 16) & 1u)) >> 16);  // RNE
}
__device__ __forceinline__ float b2f(unsigned short h) {
    union { unsigned int u; float f; } v; v.u = ((unsigned int)h) << 16;
    return v.f;
}
__device__ __forceinline__ void gload_lds16(const void* g, void* l) {
    __builtin_amdgcn_global_load_lds((const __attribute__((address_space(1))) void*)g,
                                     (__attribute__((address_space(3))) void*)l, 16, 0, 0);
}

// ---------------- prep: all weight transposes + activation casts, ONE dispatch ----------------
__device__ __forceinline__ void trans_tile(const float* __restrict__ W,
                                           unsigned short* __restrict__ Wt,
                                           int K, int N, int local) {
    __shared__ float t[32][33];
    const int ntx = N >> 5;
    const int bx = local % ntx, by = local / ntx;
    const int n0 = bx * 32, k0 = by * 32;
    const int tx = threadIdx.x & 31, ty = threadIdx.x >> 5;   // 32 x 8
#pragma unroll
    for (int i = 0; i < 4; i++)
        t[ty + i * 8][tx] = W[(size_t)(k0 + ty + i * 8) * N + n0 + tx];
    __syncthreads();
#pragma unroll
    for (int i = 0; i < 4; i++) {
        const int n = ty + i * 8;
        Wt[(size_t)(n0 + n) * K + k0 + tx] = f2b(t[tx][n]);
    }
}
__device__ __forceinline__ void cast_blk(const float* __restrict__ in,
                                         unsigned short* __restrict__ out, int local) {
    const int i = (local * 256 + threadIdx.x) * 8;
    float4 a = *(const float4*)(in + i);
    float4 b = *(const float4*)(in + i + 4);
    unsigned short r[8] = {f2b(a.x), f2b(a.y), f2b(a.z), f2b(a.w),
                           f2b(b.x), f2b(b.y), f2b(b.z), f2b(b.w)};
    *(uint4*)(out + i) = *(const uint4*)r;
}

__global__ __launch_bounds__(256) void prep(
    const float* Wqkv, const float* Wo1, const float* Wkv, const float* Wq,
    const float* Wo2, const float* W1, const float* W2,
    const float* x, const float* y,
    unsigned short* pWqkvT, unsigned short* pWo1T, unsigned short* pWkvT,
    unsigned short* pWqT, unsigned short* pWo2T, unsigned short* pW1T,
    unsigned short* pW2T, unsigned short* pxbf, unsigned short* pybf) {
    const int bid = blockIdx.x;
    if      (bid < 3072)  trans_tile(Wqkv, pWqkvT, 1024, 3072, bid);
    else if (bid < 4096)  trans_tile(Wo1,  pWo1T,  1024, 1024, bid - 3072);
    else if (bid < 6144)  trans_tile(Wkv,  pWkvT,  1024, 2048, bid - 4096);
    else if (bid < 7168)  trans_tile(Wq,   pWqT,   1024, 1024, bid - 6144);
    else if (bid < 8192)  trans_tile(Wo2,  pWo2T,  1024, 1024, bid - 7168);
    else if (bid < 12288) trans_tile(W1,   pW1T,   1024, 4096, bid - 8192);
    else if (bid < 16384) trans_tile(W2,   pW2T,   4096, 1024, bid - 12288);
    else if (bid < 18432) cast_blk(x, pxbf, bid - 16384);
    else                  cast_blk(y, pybf, bid - 18432);
}

// ---------------- bf16 MFMA GEMM (128x128, 2-barrier): C = A @ Bt^T + bias ----------------
template <int RELU, int WF32, int WB16>
__global__ __launch_bounds__(256) void gemm_bt(const unsigned short* __restrict__ A,
                                               const unsigned short* __restrict__ Bt,
                                               const float* __restrict__ bias,
                                               float* __restrict__ Cf,
                                               unsigned short* __restrict__ Cb,
                                               int M, int N, int K) {
    __shared__ __align__(16) unsigned short As[128 * 32];
    __shared__ __align__(16) unsigned short Bs[128 * 32];
    const int tid  = threadIdx.x;
    const int lane = tid & 63;
    const int w    = tid >> 6;
    const int m0   = blockIdx.y << 7;
    const int n0   = blockIdx.x << 7;
    const int wr   = (w >> 1) << 6;
    const int wc   = (w & 1) << 6;
    const int srow = lane >> 2;
    const int scol = (lane & 3) << 3;

    f32x4 acc[4][4];
#pragma unroll
    for (int mi = 0; mi < 4; mi++)
#pragma unroll
        for (int ni = 0; ni < 4; ni++) acc[mi][ni] = (f32x4){0.f, 0.f, 0.f, 0.f};

    for (int k0 = 0; k0 < K; k0 += 32) {
#pragma unroll
        for (int t = 0; t < 2; t++) {
            const int rg  = w * 2 + t;
            const int row = (rg << 4) + srow;
            gload_lds16(A  + (size_t)(m0 + row) * K + k0 + scol, (char*)As + (rg << 10));
            gload_lds16(Bt + (size_t)(n0 + row) * K + k0 + scol, (char*)Bs + (rg << 10));
        }
        __syncthreads();
        const int fr = lane & 15;
        const int fk = (lane >> 4) << 3;
        bf16x8 af[4], bfr[4];
#pragma unroll
        for (int i = 0; i < 4; i++) {
            af[i]  = *(const bf16x8*)(As + (wr + (i << 4) + fr) * 32 + fk);
            bfr[i] = *(const bf16x8*)(Bs + (wc + (i << 4) + fr) * 32 + fk);
        }
#pragma unroll
        for (int mi = 0; mi < 4; mi++)
#pragma unroll
            for (int ni = 0; ni < 4; ni++)
                acc[mi][ni] = __builtin_amdgcn_mfma_f32_16x16x32_bf16(af[mi], bfr[ni], acc[mi][ni], 0, 0, 0);
        __syncthreads();
    }

    const int fr = lane & 15;
    const int fq = lane >> 4;
#pragma unroll
    for (int mi = 0; mi < 4; mi++) {
#pragma unroll
        for (int ni = 0; ni < 4; ni++) {
            const int col = n0 + wc + (ni << 4) + fr;
            const float bv = bias[col];
#pragma unroll
            for (int i = 0; i < 4; i++) {
                const int row = m0 + wr + (mi << 4) + (fq << 2) + i;
                float v = acc[mi][ni][i] + bv;
                if (RELU) v = fmaxf(v, 0.f);
                if (WF32) Cf[(size_t)row * N + col] = v;
                if (WB16) Cb[(size_t)row * N + col] = f2b(v);
            }
        }
    }
}

// ---------------- bf16 MFMA GEMM (256x256, 8-wave, 4-phase counted-vmcnt dbuf) ----------------
template <int RELU, int WF32, int WB16>
__global__ __launch_bounds__(512, 2) void gemm256(const unsigned short* __restrict__ A,
                                                  const unsigned short* __restrict__ Bt,
                                                  const float* __restrict__ bias,
                                                  float* __restrict__ Cf,
                                                  unsigned short* __restrict__ Cb,
                                                  int M, int N, int K) {
    __shared__ __align__(16) unsigned short lds[2][2][256 * 64];   // [buf][0=A,1=B]
    const int tid  = threadIdx.x;
    const int lane = tid & 63;
    const int w    = tid >> 6;        // 0..7
    const int q15  = lane & 15;
    const int g    = lane >> 4;       // 0..3
    const int m0   = blockIdx.y << 8;
    const int n0   = blockIdx.x << 8;
    const int wr   = (w >> 2) << 7;
    const int wc   = (w & 3) << 6;

    f32x4 acc[8][4];
#pragma unroll
    for (int m = 0; m < 8; m++)
#pragma unroll
        for (int n = 0; n < 4; n++) acc[m][n] = (f32x4){0.f, 0.f, 0.f, 0.f};

    const int NT = K >> 6;

    auto stage = [&](int which, int buf, int h, int kt, const unsigned short* src, int base0) {
        char* ldsb = (char*)&lds[buf][which][0];
#pragma unroll
        for (int j = 0; j < 2; j++) {
            const int c    = (w << 7) + (j << 6) + lane;
            const int r    = c >> 3, ci = c & 7;
            const int trow = ((r >> 6) << 7) + (h << 6) + (r & 63);
            const int r0   = (w << 4) + (j << 3);
            const int tr0  = ((r0 >> 6) << 7) + (h << 6) + (r0 & 63);
            gload_lds16(src + (size_t)(base0 + trow) * K + (kt << 6) + ((ci ^ (r & 7)) << 3),
                        ldsb + tr0 * 128);
        }
    };
    auto ldA = [&](int buf, int row, int kc) -> bf16x8 {
        return *(const bf16x8*)((const char*)&lds[buf][0][0] + row * 128 + ((kc ^ (row & 7)) << 4));
    };
    auto ldB = [&](int buf, int row, int kc) -> bf16x8 {
        return *(const bf16x8*)((const char*)&lds[buf][1][0] + row * 128 + ((kc ^ (row & 7)) << 4));
    };

    stage(1, 0, 0, 0, Bt, n0);
    stage(1, 0, 1, 0, Bt, n0);
    stage(0, 0, 0, 0, A, m0);
    stage(0, 0, 1, 0, A, m0);

    for (int t = 0; t < NT; ++t) {
        const int buf = t & 1, nb = buf ^ 1;
        const bool st = (t + 1 < NT);
        bf16x8 bfr[4], af[4];

        if (st) { stage(1, nb, 0, t + 1, Bt, n0);
                  asm volatile("s_waitcnt vmcnt(4)" ::: "memory"); }
        else    { asm volatile("s_waitcnt vmcnt(2)" ::: "memory"); }
        SBAR();
#pragma unroll
        for (int n = 0; n < 4; n++) bfr[n] = ldB(buf, wc + n * 16 + q15, g);
#pragma unroll
        for (int m = 0; m < 4; m++) af[m]  = ldA(buf, wr + m * 16 + q15, g);
        __builtin_amdgcn_s_setprio(1);
#pragma unroll
        for (int m = 0; m < 4; m++)
#pragma unroll
            for (int n = 0; n < 4; n++)
                acc[m][n] = __builtin_amdgcn_mfma_f32_16x16x32_bf16(af[m], bfr[n], acc[m][n], 0, 0, 0);
        __builtin_amdgcn_s_setprio(0);
        SBAR();

        if (st) { stage(1, nb, 1, t + 1, Bt, n0);
                  asm volatile("s_waitcnt vmcnt(4)" ::: "memory"); }
        else    { asm volatile("s_waitcnt vmcnt(0)" ::: "memory"); }
        SBAR();
#pragma unroll
        for (int m = 0; m < 4; m++) af[m] = ldA(buf, wr + 64 + m * 16 + q15, g);
        __builtin_amdgcn_s_setprio(1);
#pragma unroll
        for (int m = 0; m < 4; m++)
#pragma unroll
            for (int n = 0; n < 4; n++)
                acc[4 + m][n] = __builtin_amdgcn_mfma_f32_16x16x32_bf16(af[m], bfr[n], acc[4 + m][n], 0, 0, 0);
        __builtin_amdgcn_s_setprio(0);
        SBAR();

        if (st) stage(0, nb, 0, t + 1, A, m0);
        SBAR();
#pragma unroll
        for (int n = 0; n < 4; n++) bfr[n] = ldB(buf, wc + n * 16 + q15, 4 + g);
#pragma unroll
        for (int m = 0; m < 4; m++) af[m]  = ldA(buf, wr + m * 16 + q15, 4 + g);
        __builtin_amdgcn_s_setprio(1);
#pragma unroll
        for (int m = 0; m < 4; m++)
#pragma unroll
            for (int n = 0; n < 4; n++)
                acc[m][n] = __builtin_amdgcn_mfma_f32_16x16x32_bf16(af[m], bfr[n], acc[m][n], 0, 0, 0);
        __builtin_amdgcn_s_setprio(0);
        SBAR();

        if (st) stage(0, nb, 1, t + 1, A, m0);
        SBAR();
#pragma unroll
        for (int m = 0; m < 4; m++) af[m] = ldA(buf, wr + 64 + m * 16 + q15, 4 + g);
        __builtin_amdgcn_s_setprio(1);
#pragma unroll
        for (int m = 0; m < 4; m++)
#pragma unroll
            for (int n = 0; n < 4; n++)
                acc[4 + m][n] = __builtin_amdgcn_mfma_f32_16x16x32_bf16(af[m], bfr[n], acc[4 + m][n], 0, 0, 0);
        __builtin_amdgcn_s_setprio(0);
        SBAR();
    }

#pragma unroll
    for (int mh = 0; mh < 2; mh++)
#pragma unroll
        for (int mf = 0; mf < 4; mf++)
#pragma unroll
            for (int nf = 0; nf < 4; nf++) {
                const int col = n0 + wc + nf * 16 + q15;
                const float bv = bias[col];
#pragma unroll
                for (int i = 0; i < 4; i++) {
                    const int row = m0 + wr + mh * 64 + mf * 16 + (g << 2) + i;
                    float v = acc[mh * 4 + mf][nf][i] + bv;
                    if (RELU) v = fmaxf(v, 0.f);
                    if (WF32) Cf[(size_t)row * N + col] = v;
                    if (WB16) Cb[(size_t)row * N + col] = f2b(v);
                }
            }
}

// ---------------- split-K gemm256: partial C (f32, no bias) per blockIdx.z K-chunk ----------------
__global__ __launch_bounds__(512, 2) void gemm256sk(const unsigned short* __restrict__ A,
                                                    const unsigned short* __restrict__ Bt,
                                                    float* __restrict__ Cpart,
                                                    int M, int N, int Kstride, int Kc) {
    __shared__ __align__(16) unsigned short lds[2][2][256 * 64];
    const int tid  = threadIdx.x;
    const int lane = tid & 63;
    const int w    = tid >> 6;
    const int q15  = lane & 15;
    const int g    = lane >> 4;
    const int m0   = blockIdx.y << 8;
    const int n0   = blockIdx.x << 8;
    const int wr   = (w >> 2) << 7;
    const int wc   = (w & 3) << 6;
    const int koff = blockIdx.z * Kc;

    f32x4 acc[8][4];
#pragma unroll
    for (int m = 0; m < 8; m++)
#pragma unroll
        for (int n = 0; n < 4; n++) acc[m][n] = (f32x4){0.f, 0.f, 0.f, 0.f};

    const int NT = Kc >> 6;

    auto stage = [&](int which, int buf, int h, int kt, const unsigned short* src, int base0) {
        char* ldsb = (char*)&lds[buf][which][0];
#pragma unroll
        for (int j = 0; j < 2; j++) {
            const int c    = (w << 7) + (j << 6) + lane;
            const int r    = c >> 3, ci = c & 7;
            const int trow = ((r >> 6) << 7) + (h << 6) + (r & 63);
            const int r0   = (w << 4) + (j << 3);
            const int tr0  = ((r0 >> 6) << 7) + (h << 6) + (r0 & 63);
            gload_lds16(src + (size_t)(base0 + trow) * Kstride + koff + (kt << 6) + ((ci ^ (r & 7)) << 3),
                        ldsb + tr0 * 128);
        }
    };
    auto ldA = [&](int buf, int row, int kc) -> bf16x8 {
        return *(const bf16x8*)((const char*)&lds[buf][0][0] + row * 128 + ((kc ^ (row & 7)) << 4));
    };
    auto ldB = [&](int buf, int row, int kc) -> bf16x8 {
        return *(const bf16x8*)((const char*)&lds[buf][1][0] + row * 128 + ((kc ^ (row & 7)) << 4));
    };

    stage(1, 0, 0, 0, Bt, n0);
    stage(1, 0, 1, 0, Bt, n0);
    stage(0, 0, 0, 0, A, m0);
    stage(0, 0, 1, 0, A, m0);

    for (int t = 0; t < NT; ++t) {
        const int buf = t & 1, nb = buf ^ 1;
        const bool st = (t + 1 < NT);
        bf16x8 bfr[4], af[4];

        if (st) { stage(1, nb, 0, t + 1, Bt, n0);
                  asm volatile("s_waitcnt vmcnt(4)" ::: "memory"); }
        else    { asm volatile("s_waitcnt vmcnt(2)" ::: "memory"); }
        SBAR();
#pragma unroll
        for (int n = 0; n < 4; n++) bfr[n] = ldB(buf, wc + n * 16 + q15, g);
#pragma unroll
        for (int m = 0; m < 4; m++) af[m]  = ldA(buf, wr + m * 16 + q15, g);
        __builtin_amdgcn_s_setprio(1);
#pragma unroll
        for (int m = 0; m < 4; m++)
#pragma unroll
            for (int n = 0; n < 4; n++)
                acc[m][n] = __builtin_amdgcn_mfma_f32_16x16x32_bf16(af[m], bfr[n], acc[m][n], 0, 0, 0);
        __builtin_amdgcn_s_setprio(0);
        SBAR();

        if (st) { stage(1, nb, 1, t + 1, Bt, n0);
                  asm volatile("s_waitcnt vmcnt(4)" ::: "memory"); }
        else    { asm volatile("s_waitcnt vmcnt(0)" ::: "memory"); }
        SBAR();
#pragma unroll
        for (int m = 0; m < 4; m++) af[m] = ldA(buf, wr + 64 + m * 16 + q15, g);
        __builtin_amdgcn_s_setprio(1);
#pragma unroll
        for (int m = 0; m < 4; m++)
#pragma unroll
            for (int n = 0; n < 4; n++)
                acc[4 + m][n] = __builtin_amdgcn_mfma_f32_16x16x32_bf16(af[m], bfr[n], acc[4 + m][n], 0, 0, 0);
        __builtin_amdgcn_s_setprio(0);
        SBAR();

        if (st) stage(0, nb, 0, t + 1, A, m0);
        SBAR();
#pragma unroll
        for (int n = 0; n < 4; n++) bfr[n] = ldB(buf, wc + n * 16 + q15, 4 + g);
#pragma unroll
        for (int m = 0; m < 4; m++) af[m]  = ldA(buf, wr + m * 16 + q15, 4 + g);
        __builtin_amdgcn_s_setprio(1);
#pragma unroll
        for (int m = 0; m < 4; m++)
#pragma unroll
            for (int n = 0; n < 4; n++)
                acc[m][n] = __builtin_amdgcn_mfma_f32_16x16x32_bf16(af[m], bfr[n], acc[m][n], 0, 0, 0);
        __builtin_amdgcn_s_setprio(0);
        SBAR();

        if (st) stage(0, nb, 1, t + 1, A, m0);
        SBAR();
#pragma unroll
        for (int m = 0; m < 4; m++) af[m] = ldA(buf, wr + 64 + m * 16 + q15, 4 + g);
        __builtin_amdgcn_s_setprio(1);
#pragma unroll
        for (int m = 0; m < 4; m++)
#pragma unroll
            for (int n = 0; n < 4; n++)
                acc[4 + m][n] = __builtin_amdgcn_mfma_f32_16x16x32_bf16(af[m], bfr[n], acc[4 + m][n], 0, 0, 0);
        __builtin_amdgcn_s_setprio(0);
        SBAR();
    }

    float* Cp = Cpart + (size_t)blockIdx.z * M * N;
#pragma unroll
    for (int mh = 0; mh < 2; mh++)
#pragma unroll
        for (int mf = 0; mf < 4; mf++)
#pragma unroll
            for (int nf = 0; nf < 4; nf++) {
                const int col = n0 + wc + nf * 16 + q15;
#pragma unroll
                for (int i = 0; i < 4; i++) {
                    const int row = m0 + wr + mh * 64 + mf * 16 + (g << 2) + i;
                    Cp[(size_t)row * N + col] = acc[mh * 4 + mf][nf][i];
                }
            }
}

// ---------------- residual + LayerNorm (row = 1024) ----------------
template <int WB16>
__global__ __launch_bounds__(256) void resid_ln(const float* __restrict__ xin,
                                                const float* __restrict__ res,
                                                const float* __restrict__ g,
                                                const float* __restrict__ b,
                                                float* __restrict__ outf,
                                                unsigned short* __restrict__ outb) {
    const int row = blockIdx.x;
    const int tid = threadIdx.x;
    const size_t base = (size_t)row * 1024 + tid * 4;
    float4 xv = *(const float4*)(xin + base);
    float4 rv = *(const float4*)(res + base);
    const float v0 = xv.x + rv.x, v1 = xv.y + rv.y, v2 = xv.z + rv.z, v3 = xv.w + rv.w;
    float s  = v0 + v1 + v2 + v3;
    float sq = v0 * v0 + v1 * v1 + v2 * v2 + v3 * v3;
#pragma unroll
    for (int off = 32; off; off >>= 1) { s += __shfl_xor(s, off); sq += __shfl_xor(sq, off); }
    __shared__ float red[8];
    if ((tid & 63) == 0) { red[tid >> 6] = s; red[4 + (tid >> 6)] = sq; }
    __syncthreads();
    s  = red[0] + red[1] + red[2] + red[3];
    sq = red[4] + red[5] + red[6] + red[7];
    const float mean = s * (1.0f / 1024.0f);
    const float var  = sq * (1.0f / 1024.0f) - mean * mean;
    const float inv  = rsqrtf(var + 1e-5f);
    const int col = tid * 4;
    float4 gv = *(const float4*)(g + col);
    float4 bv = *(const float4*)(b + col);
    const float o0 = (v0 - mean) * inv * gv.x + bv.x;
    const float o1 = (v1 - mean) * inv * gv.y + bv.y;
    const float o2 = (v2 - mean) * inv * gv.z + bv.z;
    const float o3 = (v3 - mean) * inv * gv.w + bv.w;
    float4 ov = {o0, o1, o2, o3};
    *(float4*)(outf + base) = ov;
    if (WB16) {
        uint2 u;
        u.x = (unsigned int)f2b(o0) | ((unsigned int)f2b(o1) << 16);
        u.y = (unsigned int)f2b(o2) | ((unsigned int)f2b(o3) << 16);
        *(uint2*)(outb + base) = u;
    }
}

// ---------------- 4-partial reduce + bias + residual + LayerNorm ----------------
__global__ __launch_bounds__(256) void resid_ln4(const float* __restrict__ part,
                                                 const float* __restrict__ bias,
                                                 const float* __restrict__ res,
                                                 const float* __restrict__ g,
                                                 const float* __restrict__ b,
                                                 float* __restrict__ outf) {
    const int row = blockIdx.x;
    const int tid = threadIdx.x;
    const size_t base = (size_t)row * 1024 + tid * 4;
    const size_t cs = (size_t)MROWS * 1024;
    float4 a0 = *(const float4*)(part + base);
    float4 a1 = *(const float4*)(part + cs + base);
    float4 a2 = *(const float4*)(part + 2 * cs + base);
    float4 a3 = *(const float4*)(part + 3 * cs + base);
    float4 rv = *(const float4*)(res + base);
    float4 bb = *(const float4*)(bias + tid * 4);
    const float v0 = a0.x + a1.x + a2.x + a3.x + bb.x + rv.x;
    const float v1 = a0.y + a1.y + a2.y + a3.y + bb.y + rv.y;
    const float v2 = a0.z + a1.z + a2.z + a3.z + bb.z + rv.z;
    const float v3 = a0.w + a1.w + a2.w + a3.w + bb.w + rv.w;
    float s  = v0 + v1 + v2 + v3;
    float sq = v0 * v0 + v1 * v1 + v2 * v2 + v3 * v3;
#pragma unroll
    for (int off = 32; off; off >>= 1) { s += __shfl_xor(s, off); sq += __shfl_xor(sq, off); }
    __shared__ float red[8];
    if ((tid & 63) == 0) { red[tid >> 6] = s; red[4 + (tid >> 6)] = sq; }
    __syncthreads();
    s  = red[0] + red[1] + red[2] + red[3];
    sq = red[4] + red[5] + red[6] + red[7];
    const float mean = s * (1.0f / 1024.0f);
    const float var  = sq * (1.0f / 1024.0f) - mean * mean;
    const float inv  = rsqrtf(var + 1e-5f);
    const int col = tid * 4;
    float4 gv = *(const float4*)(g + col);
    float4 bv = *(const float4*)(b + col);
    float4 ov = {(v0 - mean) * inv * gv.x + bv.x, (v1 - mean) * inv * gv.y + bv.y,
                 (v2 - mean) * inv * gv.z + bv.z, (v3 - mean) * inv * gv.w + bv.w};
    *(float4*)(outf + base) = ov;
}

// ---------------- MFMA flash attention v3: QBLK=128, KVBLK=64, dbuf K/V/Vt, ONE barrier/tile ----------------
// LDS 64KB: Kls[2] 16K + Vraw[2] 16K + VtQ[2] 16K (Q prologue) + P 16K -> 2 blocks/CU.
// Per tile: mask loads -> K/V(t+1) prefetch -> V-transpose(buf) -> QK^T(buf) -> softmax
//           (compiler waits vmcnt for mask only) -> P write -> syncthreads -> PV.
__global__ __launch_bounds__(512) void attn_mfma3(
    const unsigned short* __restrict__ Qb, int q_rs, int q_ho,
    const unsigned short* __restrict__ Kb, int k_rs, int k_ho,
    const unsigned short* __restrict__ Vb, int v_rs, int v_ho,
    const float* __restrict__ mask,
    unsigned short* __restrict__ Ob, int o_rs, int o_ho) {
    __shared__ __align__(16) unsigned short Kls[2][64 * 64];
    __shared__ __align__(16) unsigned short Vraw[2][64 * 64];
    __shared__ __align__(16) unsigned short VtQ[2][64 * 64];   // Q (prologue) then Vt dbuf
    __shared__ __align__(16) unsigned short Pls[8][16 * 64];

    const int tid  = threadIdx.x;
    const int lane = tid & 63;
    const int w    = tid >> 6;        // 0..7
    const int g    = lane >> 4;
    const int q15  = lane & 15;
    const int swz  = (lane & 7) << 4;
    const int bh   = blockIdx.y;
    const int b    = bh >> 4, h = bh & 15;
    const int q0   = blockIdx.x << 7;   // QBLK=128
    const size_t rowbase = (size_t)b * SEQ;

    char* Tc = (char*)&VtQ[0][0];       // 16KB contiguous
    char* Pc = (char*)(&Pls[w][0]);

    const int hq = h * q_ho, hk = h * k_ho, hv = h * v_ho;

    auto stage64 = [&](const unsigned short* base, int rs, int hoff, int row0, char* ldsb) {
        const int c = tid;
        const int r = c >> 3, ci = c & 7;
        gload_lds16(base + (rowbase + row0 + r) * (size_t)rs + hoff + ((ci ^ (r & 7)) << 3),
                    ldsb + ((c >> 6) << 10));
    };

    // prologue: Q (128 rows) into VtQ, K0/V0 into buf0
#pragma unroll
    for (int bb = 0; bb < 2; bb++) {
        const int c = tid + (bb << 9);
        const int r = c >> 3, ci = c & 7;
        gload_lds16(Qb + (rowbase + q0 + r) * (size_t)q_rs + hq + ((ci ^ (r & 7)) << 3),
                    Tc + ((c >> 6) << 10));
    }
    stage64(Kb, k_rs, hk, 0, (char*)&Kls[0][0]);
    stage64(Vb, v_rs, hv, 0, (char*)&Vraw[0][0]);

    float m_run = -3.0e38f, l_run = 0.f;
    f32x4 oacc[4];
#pragma unroll
    for (int fd = 0; fd < 4; fd++) oacc[fd] = (f32x4){0.f, 0.f, 0.f, 0.f};

    __syncthreads();     // Q/K0/V0 landed (drains vmcnt)
    bf16x8 qf[2];
#pragma unroll
    for (int s = 0; s < 2; s++)
        qf[s] = *(const bf16x8*)(Tc + (w * 16 + q15) * 128 + (((s << 6) + (g << 4)) ^ swz));
    __syncthreads();     // all waves hoisted Q before Vt overwrites

    const float* mrow_ptr = mask + (size_t)(q0 + w * 16 + q15) * SEQ;

    for (int t = 0; t < 32; t++) {
        const int buf = t & 1, nb = buf ^ 1;
        const int kv0 = t << 6;
        char* Kc  = (char*)&Kls[buf][0];
        char* Vc  = (char*)&Vraw[buf][0];
        char* Vtc = (char*)&VtQ[buf][0];

        // (A) mask loads first
        float4 mk4[4];
#pragma unroll
        for (int f = 0; f < 4; f++)
            mk4[f] = *(const float4*)(mrow_ptr + kv0 + f * 16 + g * 4);
        // (B) prefetch next K/V into other buffers
        if (t < 31) {
            stage64(Kb, k_rs, hk, kv0 + 64, (char*)&Kls[nb][0]);
            stage64(Vb, v_rs, hv, kv0 + 64, (char*)&Vraw[nb][0]);
        }
        // (C) V transpose: Vraw[buf][kv][d] -> Vt[buf][d=lane][kv-chunk=w]
        {
            unsigned short t8[8];
#pragma unroll
            for (int m = 0; m < 8; m++)
                t8[m] = *(const unsigned short*)(Vc + (w * 8 + m) * 128 + ((2 * lane) ^ (m << 4)));
            *(uint4*)(Vtc + lane * 128 + ((w << 4) ^ swz)) = *(const uint4*)t8;
        }
        // (D) QK^T (swapped): sacc[f] = S^T[kv=f*16+g*4+r][q=q15]
        f32x4 sacc[4];
#pragma unroll
        for (int f = 0; f < 4; f++) sacc[f] = (f32x4){0.f, 0.f, 0.f, 0.f};
#pragma unroll
        for (int s = 0; s < 2; s++)
#pragma unroll
            for (int f = 0; f < 4; f++) {
                bf16x8 kf = *(const bf16x8*)(Kc + (f * 16 + q15) * 128 + (((s << 6) + (g << 4)) ^ swz));
                sacc[f] = __builtin_amdgcn_mfma_f32_16x16x32_bf16(kf, qf[s], sacc[f], 0, 0, 0);
            }
        // (E) softmax with defer-max (THR=8)
        float p[4][4];
        float mt = -3.0e38f;
#pragma unroll
        for (int f = 0; f < 4; f++) {
            const float* mkp = (const float*)&mk4[f];
#pragma unroll
            for (int r = 0; r < 4; r++) {
                const float v = sacc[f][r] * 0.125f + mkp[r];
                p[f][r] = v;
                mt = fmaxf(mt, v);
            }
        }
        mt = fmaxf(mt, __shfl_xor(mt, 16));
        mt = fmaxf(mt, __shfl_xor(mt, 32));
        const bool rescale = !__all(mt <= m_run + 8.0f);
        float alpha = 1.0f;
        if (rescale) {
            const float mnew = fmaxf(m_run, mt);
            alpha = __expf(m_run - mnew);
            m_run = mnew;
        }
        float lsum = 0.f;
#pragma unroll
        for (int f = 0; f < 4; f++)
#pragma unroll
            for (int r = 0; r < 4; r++) {
                const float e = __expf(p[f][r] - m_run);
                p[f][r] = e;
                lsum += e;
            }
        lsum += __shfl_xor(lsum, 16);
        lsum += __shfl_xor(lsum, 32);
        l_run = l_run * alpha + lsum;
        // (F) P -> bf16 into per-wave P_lds
#pragma unroll
        for (int f = 0; f < 4; f++) {
            const unsigned int w0 = (unsigned int)f2b(p[f][0]) | ((unsigned int)f2b(p[f][1]) << 16);
            const unsigned int w1 = (unsigned int)f2b(p[f][2]) | ((unsigned int)f2b(p[f][3]) << 16);
            const int bbase = ((f << 5) + (g << 3)) ^ swz;
            *(unsigned int*)(Pc + q15 * 128 + bbase)     = w0;
            *(unsigned int*)(Pc + q15 * 128 + bbase + 4) = w1;
        }
        // (G) the ONE barrier: publishes Vt(t)+P(t); drains K/V(t+1) loads
        __syncthreads();
        // (H) rescale O + PV
        if (rescale) {
            float ar[4];
#pragma unroll
            for (int r = 0; r < 4; r++) ar[r] = __shfl(alpha, (g << 4) + (g << 2) + r);
#pragma unroll
            for (int fd = 0; fd < 4; fd++)
#pragma unroll
                for (int r = 0; r < 4; r++) oacc[fd][r] *= ar[r];
        }
#pragma unroll
        for (int s = 0; s < 2; s++) {
            const bf16x8 pf = *(const bf16x8*)(Pc + q15 * 128 + (((s << 6) + (g << 4)) ^ swz));
#pragma unroll
            for (int fd = 0; fd < 4; fd++) {
                const bf16x8 vf = *(const bf16x8*)(Vtc + (fd * 16 + q15) * 128 + (((s << 6) + (g << 4)) ^ swz));
                oacc[fd] = __builtin_amdgcn_mfma_f32_16x16x32_bf16(pf, vf, oacc[fd], 0, 0, 0);
            }
        }
    }

    const float rl = 1.0f / l_run;
    float invr[4];
#pragma unroll
    for (int r = 0; r < 4; r++) invr[r] = __shfl(rl, (g << 4) + (g << 2) + r);
    const size_t orow0 = rowbase + q0 + w * 16;
#pragma unroll
    for (int fd = 0; fd < 4; fd++)
#pragma unroll
        for (int r = 0; r < 4; r++) {
            const int qq = (g << 2) + r;
            Ob[(orow0 + qq) * (size_t)o_rs + h * o_ho + fd * 16 + q15] = f2b(oacc[fd][r] * invr[r]);
        }
}

// ---------------- orchestration ----------------
extern "C" void kernel_launch(void* const* d_in, const int* in_sizes, int n_in,
                              void* d_out, int out_size, void* d_ws, size_t ws_size,
                              hipStream_t stream) {
    const float* x     = (const float*)d_in[0];
    const float* y     = (const float*)d_in[1];
    const float* mask1 = (const float*)d_in[2];
    const float* mask2 = (const float*)d_in[3];
    const float* Wqkv  = (const float*)d_in[4];
    const float* bqkv  = (const float*)d_in[5];
    const float* Wo1   = (const float*)d_in[6];
    const float* bo1   = (const float*)d_in[7];
    const float* Wkv   = (const float*)d_in[8];
    const float* bkv   = (const float*)d_in[9];
    const float* Wq    = (const float*)d_in[10];
    const float* bq    = (const float*)d_in[11];
    const float* Wo2   = (const float*)d_in[12];
    const float* bo2   = (const float*)d_in[13];
    const float* g1    = (const float*)d_in[14];
    const float* b1    = (const float*)d_in[15];
    const float* g2    = (const float*)d_in[16];
    const float* b2    = (const float*)d_in[17];
    const float* g3    = (const float*)d_in[18];
    const float* b3    = (const float*)d_in[19];
    const float* W1    = (const float*)d_in[20];
    const float* bw1   = (const float*)d_in[21];
    const float* W2    = (const float*)d_in[22];
    const float* bw2   = (const float*)d_in[23];

    char* ws = (char*)d_ws;
    const size_t o_WqkvT = 0;
    const size_t o_Wo1T  = o_WqkvT + 6291456;
    const size_t o_WkvT  = o_Wo1T  + 2097152;
    const size_t o_WqT   = o_WkvT  + 4194304;
    const size_t o_Wo2T  = o_WqT   + 2097152;
    const size_t o_W1T   = o_Wo2T  + 2097152;
    const size_t o_W2T   = o_W1T   + 8388608;
    const size_t o_xbf   = o_W2T   + 8388608;
    const size_t o_ybf   = o_xbf   + 8388608;
    const size_t o_qkv   = o_ybf   + 8388608;
    const size_t o_vals  = o_qkv   + 25165824;
    const size_t o_tmp   = o_vals  + 8388608;
    const size_t o_y1    = o_tmp   + 16777216;
    const size_t o_y1bf  = o_y1    + 16777216;
    const size_t o_y2    = o_y1bf  + 8388608;
    const size_t o_y2bf  = o_y2    + 16777216;
    const size_t o_kv    = o_qkv;
    const size_t o_q2    = o_qkv + 16777216;
    const size_t o_hbf   = o_xbf;
    const size_t o_part  = o_qkv;   // 64MB partials over dead [qkv..y1bf) at W2 time

    unsigned short* pWqkvT = (unsigned short*)(ws + o_WqkvT);
    unsigned short* pWo1T  = (unsigned short*)(ws + o_Wo1T);
    unsigned short* pWkvT  = (unsigned short*)(ws + o_WkvT);
    unsigned short* pWqT   = (unsigned short*)(ws + o_WqT);
    unsigned short* pWo2T  = (unsigned short*)(ws + o_Wo2T);
    unsigned short* pW1T   = (unsigned short*)(ws + o_W1T);
    unsigned short* pW2T   = (unsigned short*)(ws + o_W2T);
    unsigned short* pxbf   = (unsigned short*)(ws + o_xbf);
    unsigned short* pybf   = (unsigned short*)(ws + o_ybf);
    unsigned short* pqkv   = (unsigned short*)(ws + o_qkv);
    unsigned short* pvals  = (unsigned short*)(ws + o_vals);
    float*          ptmp   = (float*)(ws + o_tmp);
    float*          py1    = (float*)(ws + o_y1);
    unsigned short* py1bf  = (unsigned short*)(ws + o_y1bf);
    float*          py2    = (float*)(ws + o_y2);
    unsigned short* py2bf  = (unsigned short*)(ws + o_y2bf);
    unsigned short* pkv    = (unsigned short*)(ws + o_kv);
    unsigned short* pq2    = (unsigned short*)(ws + o_q2);
    unsigned short* phbf   = (unsigned short*)(ws + o_hbf);
    float*          pPart  = (float*)(ws + o_part);

    prep<<<dim3(20480), dim3(256), 0, stream>>>(Wqkv, Wo1, Wkv, Wq, Wo2, W1, W2, x, y,
                                                pWqkvT, pWo1T, pWkvT, pWqT, pWo2T,
                                                pW1T, pW2T, pxbf, pybf);

    // ---- self-attention ----
    gemm256<0, 0, 1><<<dim3(3072 / 256, MROWS / 256), dim3(512), 0, stream>>>(
        pybf, pWqkvT, bqkv, nullptr, pqkv, MROWS, 3072, 1024);
    attn_mfma3<<<dim3(SEQ / 128, BATCH * NHEADS), dim3(512), 0, stream>>>(
        pqkv, 3072, 192, pqkv + 64, 3072, 192, pqkv + 128, 3072, 192,
        mask1, pvals, 1024, 64);
    gemm_bt<0, 1, 0><<<dim3(1024 / 128, MROWS / 128), dim3(256), 0, stream>>>(
        pvals, pWo1T, bo1, ptmp, nullptr, MROWS, 1024, 1024);
    resid_ln<1><<<dim3(MROWS), dim3(256), 0, stream>>>(ptmp, y, g1, b1, py1, py1bf);

    // ---- cross-attention ----
    gemm256<0, 0, 1><<<dim3(2048 / 256, MROWS / 256), dim3(512), 0, stream>>>(
        pxbf, pWkvT, bkv, nullptr, pkv, MROWS, 2048, 1024);
    gemm_bt<0, 0, 1><<<dim3(1024 / 128, MROWS / 128), dim3(256), 0, stream>>>(
        py1bf, pWqT, bq, nullptr, pq2, MROWS, 1024, 1024);
    attn_mfma3<<<dim3(SEQ / 128, BATCH * NHEADS), dim3(512), 0, stream>>>(
        pq2, 1024, 64, pkv, 2048, 128, pkv + 64, 2048, 128,
        mask2, pvals, 1024, 64);
    gemm_bt<0, 1, 0><<<dim3(1024 / 128, MROWS / 128), dim3(256), 0, stream>>>(
        pvals, pWo2T, bo2, ptmp, nullptr, MROWS, 1024, 1024);
    resid_ln<1><<<dim3(MROWS), dim3(256), 0, stream>>>(ptmp, py1, g2, b2, py2, py2bf);

    // ---- FFN ----
    gemm256<1, 0, 1><<<dim3(4096 / 256, MROWS / 256), dim3(512), 0, stream>>>(
        py2bf, pW1T, bw1, nullptr, phbf, MROWS, 4096, 1024);
    gemm256sk<<<dim3(1024 / 256, MROWS / 256, 4), dim3(512), 0, stream>>>(
        phbf, pW2T, pPart, MROWS, 1024, 4096, 1024);
    resid_ln4<<<dim3(MROWS), dim3(256), 0, stream>>>(pPart, bw2, py2, g3, b3, (float*)d_out);
}